// Round 1
// baseline (3996.537 us; speedup 1.0000x reference)
//
#include <hip/hip_runtime.h>
#include <math.h>

// B=8, H=W=224, C=96, NH=3, HD=32, WS=7, SHIFT=3, N=49
// windows: 32x32 per image, 8192 total. tokens: 401408.

__global__ __launch_bounds__(256) void win_attn_kernel(
    const float* __restrict__ x,
    const float* __restrict__ qkv_w, const float* __restrict__ qkv_b,
    const float* __restrict__ proj_w, const float* __restrict__ proj_b,
    const float* __restrict__ rpb,
    float* __restrict__ xr)
{
    __shared__ float xw[49][96];    // input window
    __shared__ float qs[49][33];    // q (scaled), padded vs bank conflicts
    __shared__ float ksh[49][33];
    __shared__ float vsh[49][33];
    __shared__ float at[49][49];    // attn matrix (one head at a time)
    __shared__ float ob[49][96];    // attention output (all heads)

    const int win = blockIdx.x;
    const int b   = win >> 10;          // /1024
    const int rem = win & 1023;
    const int wh  = rem >> 5, ww = rem & 31;
    const int tid = threadIdx.x;

    // ---- load window (cyclic shift -3 applied on read) ----
    for (int idx = tid; idx < 49 * 96; idx += 256) {
        int t = idx / 96, c = idx - t * 96;
        int i = t / 7, j = t - i * 7;
        int h = wh * 7 + i + 3; if (h >= 224) h -= 224;
        int w = ww * 7 + j + 3; if (w >= 224) w -= 224;
        xw[t][c] = x[((b * 224 + h) * 224 + w) * 96 + c];
    }
    __syncthreads();

    const float scale = 0.17677669529663687f; // 32^-0.5

    for (int head = 0; head < 3; ++head) {
        // ---- q,k,v for this head: col = seg*96 + head*32 + d ----
        for (int idx = tid; idx < 49 * 96; idx += 256) {
            int t = idx / 96, c = idx - t * 96;
            int seg = c >> 5, d = c & 31;
            int col = seg * 96 + head * 32 + d;
            const float* wp = qkv_w + col;
            const float* xp = xw[t];
            float acc = qkv_b[col];
            #pragma unroll 8
            for (int kk = 0; kk < 96; ++kk) acc = fmaf(xp[kk], wp[kk * 288], acc);
            if      (seg == 0) qs[t][d]  = acc * scale;
            else if (seg == 1) ksh[t][d] = acc;
            else               vsh[t][d] = acc;
        }
        __syncthreads();

        // ---- logits + relative position bias ----
        for (int idx = tid; idx < 49 * 49; idx += 256) {
            int t = idx / 49, s = idx - t * 49;
            float acc = 0.f;
            #pragma unroll
            for (int kk = 0; kk < 32; ++kk) acc = fmaf(qs[t][kk], ksh[s][kk], acc);
            int ti = t / 7, tj = t - ti * 7;
            int si = s / 7, sj = s - si * 7;
            int bi = (ti - si + 6) * 13 + (tj - sj + 6);
            at[t][s] = acc + rpb[bi * 3 + head];
        }
        __syncthreads();

        // ---- softmax per row ----
        if (tid < 49) {
            float m = -1e30f;
            #pragma unroll
            for (int s = 0; s < 49; ++s) m = fmaxf(m, at[tid][s]);
            float sum = 0.f;
            #pragma unroll
            for (int s = 0; s < 49; ++s) { float e = __expf(at[tid][s] - m); at[tid][s] = e; sum += e; }
            float inv = 1.f / sum;
            #pragma unroll
            for (int s = 0; s < 49; ++s) at[tid][s] *= inv;
        }
        __syncthreads();

        // ---- PV ----
        for (int idx = tid; idx < 49 * 32; idx += 256) {
            int t = idx >> 5, d = idx & 31;
            float acc = 0.f;
            #pragma unroll
            for (int s = 0; s < 49; ++s) acc = fmaf(at[t][s], vsh[s][d], acc);
            ob[t][head * 32 + d] = acc;
        }
        __syncthreads();   // also protects q/k/v/at reuse next head
    }

    // ---- proj + scatter with reverse shift (+3) ----
    for (int idx = tid; idx < 49 * 96; idx += 256) {
        int t = idx / 96, c = idx - t * 96;
        float acc = proj_b[c];
        const float* wp = proj_w + c;
        const float* op = ob[t];
        #pragma unroll 8
        for (int kk = 0; kk < 96; ++kk) acc = fmaf(op[kk], wp[kk * 96], acc);
        int i = t / 7, j = t - i * 7;
        int h = wh * 7 + i + 3; if (h >= 224) h -= 224;
        int w = ww * 7 + j + 3; if (w >= 224) w -= 224;
        xr[((b * 224 + h) * 224 + w) * 96 + c] = acc;
    }
}

// LN + MLP(gelu) + residual, in-place on io. 32 tokens / block.
__global__ __launch_bounds__(256) void mlp_kernel(
    float* __restrict__ io,
    const float* __restrict__ g, const float* __restrict__ bta,
    const float* __restrict__ fc1_w, const float* __restrict__ fc1_b,
    const float* __restrict__ fc2_w, const float* __restrict__ fc2_b)
{
    __shared__ float xrt[32][97];   // raw input (residual), pad col 96 = inv_std
    __shared__ float xn [32][97];   // normalized, pad col 96 = mu
    __shared__ float hbuf[32][384]; // gelu(fc1) activations

    const int tid = threadIdx.x;
    const size_t base = (size_t)blockIdx.x * 32 * 96;

    for (int idx = tid; idx < 32 * 96; idx += 256)
        xrt[idx / 96][idx % 96] = io[base + idx];
    __syncthreads();

    if (tid < 32) {
        float s = 0.f, s2 = 0.f;
        #pragma unroll 8
        for (int c = 0; c < 96; ++c) { float v = xrt[tid][c]; s += v; s2 += v * v; }
        float mu  = s * (1.f / 96.f);
        float var = s2 * (1.f / 96.f) - mu * mu;
        xn [tid][96] = mu;
        xrt[tid][96] = rsqrtf(var + 1e-5f);
    }
    __syncthreads();

    for (int idx = tid; idx < 32 * 96; idx += 256) {
        int t = idx / 96, c = idx - (idx / 96) * 96;
        xn[t][c] = (xrt[t][c] - xn[t][96]) * xrt[t][96] * g[c] + bta[c];
    }
    __syncthreads();

    // ---- fc1 + gelu: 8 tokens x 6 cols per thread ----
    {
        const int tg = tid >> 6;        // token group: tokens tg*8 .. tg*8+7
        const int c0 = tid & 63;        // cols c0 + 64*cc, cc=0..5
        float acc[8][6];
        #pragma unroll
        for (int cc = 0; cc < 6; ++cc) {
            float bb = fc1_b[c0 + 64 * cc];
            #pragma unroll
            for (int tt = 0; tt < 8; ++tt) acc[tt][cc] = bb;
        }
        for (int k = 0; k < 96; ++k) {
            float wv[6];
            #pragma unroll
            for (int cc = 0; cc < 6; ++cc) wv[cc] = fc1_w[k * 384 + c0 + 64 * cc];
            #pragma unroll
            for (int tt = 0; tt < 8; ++tt) {
                float nv = xn[tg * 8 + tt][k];
                #pragma unroll
                for (int cc = 0; cc < 6; ++cc) acc[tt][cc] = fmaf(nv, wv[cc], acc[tt][cc]);
            }
        }
        #pragma unroll
        for (int tt = 0; tt < 8; ++tt)
            #pragma unroll
            for (int cc = 0; cc < 6; ++cc) {
                float v = acc[tt][cc];
                float ge = 0.5f * v * (1.f + erff(v * 0.70710678118654752f));
                hbuf[tg * 8 + tt][c0 + 64 * cc] = ge;
            }
    }
    __syncthreads();

    // ---- fc2 + residual: 4 tokens x 3 cols per thread ----
    {
        const int tg = tid >> 5;        // tokens tg*4 .. tg*4+3
        const int c0 = tid & 31;        // cols c0 + 32*i, i=0..2
        float acc[4][3];
        #pragma unroll
        for (int i = 0; i < 3; ++i) {
            float bb = fc2_b[c0 + 32 * i];
            #pragma unroll
            for (int tt = 0; tt < 4; ++tt) acc[tt][i] = bb;
        }
        for (int k = 0; k < 384; ++k) {
            float wv[3];
            #pragma unroll
            for (int i = 0; i < 3; ++i) wv[i] = fc2_w[k * 96 + c0 + 32 * i];
            #pragma unroll
            for (int tt = 0; tt < 4; ++tt) {
                float hv = hbuf[tg * 4 + tt][k];
                #pragma unroll
                for (int i = 0; i < 3; ++i) acc[tt][i] = fmaf(hv, wv[i], acc[tt][i]);
            }
        }
        #pragma unroll
        for (int tt = 0; tt < 4; ++tt)
            #pragma unroll
            for (int i = 0; i < 3; ++i) {
                int t = tg * 4 + tt, c = c0 + 32 * i;
                io[base + t * 96 + c] = xrt[t][c] + acc[tt][i];
            }
    }
}

extern "C" void kernel_launch(void* const* d_in, const int* in_sizes, int n_in,
                              void* d_out, int out_size, void* d_ws, size_t ws_size,
                              hipStream_t stream) {
    const float* x      = (const float*)d_in[0];
    const float* qkv_w  = (const float*)d_in[1];
    const float* qkv_b  = (const float*)d_in[2];
    const float* proj_w = (const float*)d_in[3];
    const float* proj_b = (const float*)d_in[4];
    const float* rpb    = (const float*)d_in[5];
    const float* n2g    = (const float*)d_in[6];
    const float* n2b    = (const float*)d_in[7];
    const float* fc1_w  = (const float*)d_in[8];
    const float* fc1_b  = (const float*)d_in[9];
    const float* fc2_w  = (const float*)d_in[10];
    const float* fc2_b  = (const float*)d_in[11];
    float* out = (float*)d_out;

    // K1: window attention -> writes xr (pre-MLP) into d_out (full overwrite)
    win_attn_kernel<<<8192, 256, 0, stream>>>(x, qkv_w, qkv_b, proj_w, proj_b, rpb, out);
    // K2: LN + MLP + residual, in-place on d_out
    mlp_kernel<<<401408 / 32, 256, 0, stream>>>(out, n2g, n2b, fc1_w, fc1_b, fc2_w, fc2_b);
}